// Round 1
// baseline (819.837 us; speedup 1.0000x reference)
//
#include <hip/hip_runtime.h>

#define B_ 4
#define T_ 4096
#define C_ 1024
#define M_ (B_*T_)                 // 16384
#define BTC (B_*T_*C_)             // 16777216

typedef unsigned short u16;
typedef __attribute__((ext_vector_type(8))) short bf16x8;
typedef __attribute__((ext_vector_type(4))) float f32x4;

static __device__ __forceinline__ u16 f2bf(float f) {
    unsigned u = __float_as_uint(f);
    unsigned r = (u + 0x7FFFu + ((u >> 16) & 1u)) >> 16;   // RNE
    return (u16)r;
}
static __device__ __forceinline__ float bf2f(u16 h) {
    return __uint_as_float(((unsigned)h) << 16);
}

// ---------------- prep: time-mix + bf16 cast + new_state ----------------
__global__ void prep_kernel(const float* __restrict__ x, const float* __restrict__ state,
                            const float* __restrict__ tmr, const float* __restrict__ tmk,
                            const float* __restrict__ tmv,
                            u16* __restrict__ rin, u16* __restrict__ kin, u16* __restrict__ vin,
                            float* __restrict__ new_state) {
    int idx4 = blockIdx.x * blockDim.x + threadIdx.x;
    const int n4 = BTC / 4;
    if (idx4 >= n4) return;
    const int C4 = C_ / 4;
    int c4 = idx4 % C4;
    int bt = idx4 / C4;
    int t  = bt % T_;
    int b  = bt / T_;
    float4 xc = ((const float4*)x)[idx4];
    float4 xp = (t == 0) ? ((const float4*)state)[b * C4 + c4]
                         : ((const float4*)x)[idx4 - C4];
    float4 mr = ((const float4*)tmr)[c4];
    float4 mk = ((const float4*)tmk)[c4];
    float4 mv = ((const float4*)tmv)[c4];
    ushort4 pr, pk, pv;
    pr.x = f2bf(xc.x*mr.x + xp.x*(1.f-mr.x));
    pr.y = f2bf(xc.y*mr.y + xp.y*(1.f-mr.y));
    pr.z = f2bf(xc.z*mr.z + xp.z*(1.f-mr.z));
    pr.w = f2bf(xc.w*mr.w + xp.w*(1.f-mr.w));
    pk.x = f2bf(xc.x*mk.x + xp.x*(1.f-mk.x));
    pk.y = f2bf(xc.y*mk.y + xp.y*(1.f-mk.y));
    pk.z = f2bf(xc.z*mk.z + xp.z*(1.f-mk.z));
    pk.w = f2bf(xc.w*mk.w + xp.w*(1.f-mk.w));
    pv.x = f2bf(xc.x*mv.x + xp.x*(1.f-mv.x));
    pv.y = f2bf(xc.y*mv.y + xp.y*(1.f-mv.y));
    pv.z = f2bf(xc.z*mv.z + xp.z*(1.f-mv.z));
    pv.w = f2bf(xc.w*mv.w + xp.w*(1.f-mv.w));
    ((ushort4*)rin)[idx4] = pr;
    ((ushort4*)kin)[idx4] = pk;
    ((ushort4*)vin)[idx4] = pv;
    if (t == T_ - 1) ((float4*)new_state)[b * C4 + c4] = xc;
}

// ---------------- weight cast fp32 -> bf16 ----------------
__global__ void cast_kernel(const float* __restrict__ src, u16* __restrict__ dst, int n4) {
    int i = blockIdx.x * blockDim.x + threadIdx.x;
    if (i >= n4) return;
    float4 v = ((const float4*)src)[i];
    ushort4 o;
    o.x = f2bf(v.x); o.y = f2bf(v.y); o.z = f2bf(v.z); o.w = f2bf(v.w);
    ((ushort4*)dst)[i] = o;
}

// ---------------- bf16 MFMA GEMM: C[m][n] = sum_k A[m][k] * W[n][k] ----------------
#define BM 128
#define BN 128
#define BK 32
#define EPI_SIG  0
#define EPI_EXP  1
#define EPI_BF16 2
#define EPI_F32  3

template <int EPI>
__global__ __launch_bounds__(256, 2)
void gemm_bt(const u16* __restrict__ A, const u16* __restrict__ W,
             void* __restrict__ Cptr, int M, int N, int K) {
    __shared__ u16 ldsA[2][BM * BK];
    __shared__ u16 ldsB[2][BN * BK];
    const int tid  = threadIdx.x;
    const int bn   = blockIdx.x, bm = blockIdx.y;
    const int row0 = bm * BM, col0 = bn * BN;
    const int wid  = tid >> 6, lane = tid & 63;
    const int wm   = wid >> 1, wn = wid & 1;
    const int lr   = lane & 15, kq = lane >> 4;

    f32x4 acc[4][4];
#pragma unroll
    for (int i = 0; i < 4; ++i)
#pragma unroll
        for (int j = 0; j < 4; ++j)
#pragma unroll
            for (int q = 0; q < 4; ++q) acc[i][j][q] = 0.f;

    const int rS = tid >> 2;            // 0..63
    const int kc = (tid & 3) * 8;       // 0,8,16,24

    auto stage = [&](int buf, int k0) {
#pragma unroll
        for (int h = 0; h < 2; ++h) {
            const u16* g = A + (size_t)(row0 + h * 64 + rS) * K + (k0 + kc);
            __builtin_amdgcn_global_load_lds(
                (const __attribute__((address_space(1))) void*)g,
                (__attribute__((address_space(3))) void*)&ldsA[buf][(h * 64 + rS) * BK + kc],
                16, 0, 0);
        }
#pragma unroll
        for (int h = 0; h < 2; ++h) {
            const u16* g = W + (size_t)(col0 + h * 64 + rS) * K + (k0 + kc);
            __builtin_amdgcn_global_load_lds(
                (const __attribute__((address_space(1))) void*)g,
                (__attribute__((address_space(3))) void*)&ldsB[buf][(h * 64 + rS) * BK + kc],
                16, 0, 0);
        }
    };

    stage(0, 0);
    __syncthreads();

    const int nk = K / BK;
    for (int kt = 0; kt < nk; ++kt) {
        const int cur = kt & 1;
        if (kt + 1 < nk) stage(cur ^ 1, (kt + 1) * BK);
        bf16x8 a[4], b[4];
#pragma unroll
        for (int i = 0; i < 4; ++i)
            a[i] = *(const bf16x8*)&ldsA[cur][(wm * 64 + i * 16 + lr) * BK + kq * 8];
#pragma unroll
        for (int j = 0; j < 4; ++j)
            b[j] = *(const bf16x8*)&ldsB[cur][(wn * 64 + j * 16 + lr) * BK + kq * 8];
#pragma unroll
        for (int i = 0; i < 4; ++i)
#pragma unroll
            for (int j = 0; j < 4; ++j)
                acc[i][j] = __builtin_amdgcn_mfma_f32_16x16x32_bf16(a[i], b[j], acc[i][j], 0, 0, 0);
        __syncthreads();
    }

    const int r0 = row0 + wm * 64;
    const int c0 = col0 + wn * 64;
#pragma unroll
    for (int i = 0; i < 4; ++i) {
#pragma unroll
        for (int j = 0; j < 4; ++j) {
#pragma unroll
            for (int q = 0; q < 4; ++q) {
                int rr = r0 + i * 16 + kq * 4 + q;
                int cc = c0 + j * 16 + lr;
                float v = acc[i][j][q];
                size_t o = (size_t)rr * N + cc;
                if constexpr (EPI == EPI_SIG) {
                    ((u16*)Cptr)[o] = f2bf(1.0f / (1.0f + __expf(-v)));
                } else if constexpr (EPI == EPI_EXP) {
                    ((u16*)Cptr)[o] = f2bf(__expf(v));
                } else if constexpr (EPI == EPI_BF16) {
                    ((u16*)Cptr)[o] = f2bf(v);
                } else {
                    ((float*)Cptr)[o] = v;
                }
            }
        }
    }
}

// ---------------- sequential scan over T ----------------
__global__ void scan_kernel(const u16* __restrict__ ek, const u16* __restrict__ vv,
                            const u16* __restrict__ rr, const float* __restrict__ td,
                            const float* __restrict__ state, u16* __restrict__ out) {
    int id = blockIdx.x * blockDim.x + threadIdx.x;
    if (id >= B_ * C_) return;
    int c = id & (C_ - 1);
    int b = id >> 10;
    float d = expf(td[c]);
    float s = state[id];
    size_t base = (size_t)b * T_ * C_ + c;
#pragma unroll 4
    for (int t = 0; t < T_; ++t) {
        size_t ix = base + (size_t)t * C_;
        float kvt = bf2f(ek[ix]) * bf2f(vv[ix]);
        s = s * d + kvt;
        out[ix] = f2bf(s * bf2f(rr[ix]));
    }
}

extern "C" void kernel_launch(void* const* d_in, const int* in_sizes, int n_in,
                              void* d_out, int out_size, void* d_ws, size_t ws_size,
                              hipStream_t stream) {
    const float* x     = (const float*)d_in[0];
    const float* state = (const float*)d_in[1];
    const float* W_r   = (const float*)d_in[2];
    const float* W_k   = (const float*)d_in[3];
    const float* W_v   = (const float*)d_in[4];
    const float* W_o   = (const float*)d_in[5];
    const float* tmr   = (const float*)d_in[6];
    const float* tmk   = (const float*)d_in[7];
    const float* tmv   = (const float*)d_in[8];
    const float* td    = (const float*)d_in[9];

    float* out_f     = (float*)d_out;          // [B,T,C] fp32
    float* new_state = out_f + (size_t)BTC;    // [B,C] fp32

    char* ws = (char*)d_ws;
    const size_t SZ = (size_t)BTC * 2;         // 33,554,432 B per bf16 buffer
    u16* rin   = (u16*)(ws + 0 * SZ);
    u16* kin   = (u16*)(ws + 1 * SZ);
    u16* vin   = (u16*)(ws + 2 * SZ);
    u16* rbuf  = (u16*)(ws + 3 * SZ);
    u16* ekbuf = (u16*)(ws + 4 * SZ);
    u16* vbuf  = (u16*)(ws + 5 * SZ);
    u16* wrb   = (u16*)(ws + 6 * SZ);
    u16* wkb   = wrb + (size_t)C_ * C_;
    u16* wvb   = wkb + (size_t)C_ * C_;
    u16* wob   = wvb + (size_t)C_ * C_;
    u16* outb  = vin;                          // overlay: vin dead after v-GEMM

    prep_kernel<<<(BTC / 4 + 255) / 256, 256, 0, stream>>>(
        x, state, tmr, tmk, tmv, rin, kin, vin, new_state);

    const int wn4 = (C_ * C_) / 4;
    cast_kernel<<<(wn4 + 255) / 256, 256, 0, stream>>>(W_r, wrb, wn4);
    cast_kernel<<<(wn4 + 255) / 256, 256, 0, stream>>>(W_k, wkb, wn4);
    cast_kernel<<<(wn4 + 255) / 256, 256, 0, stream>>>(W_v, wvb, wn4);
    cast_kernel<<<(wn4 + 255) / 256, 256, 0, stream>>>(W_o, wob, wn4);

    dim3 gg(C_ / BN, M_ / BM);   // (8, 128)
    gemm_bt<EPI_SIG ><<<gg, 256, 0, stream>>>(rin, wrb, (void*)rbuf,  M_, C_, C_);
    gemm_bt<EPI_EXP ><<<gg, 256, 0, stream>>>(kin, wkb, (void*)ekbuf, M_, C_, C_);
    gemm_bt<EPI_BF16><<<gg, 256, 0, stream>>>(vin, wvb, (void*)vbuf,  M_, C_, C_);

    scan_kernel<<<(B_ * C_ + 255) / 256, 256, 0, stream>>>(
        ekbuf, vbuf, rbuf, td, state, outb);

    gemm_bt<EPI_F32><<<gg, 256, 0, stream>>>(outb, wob, (void*)out_f, M_, C_, C_);
}

// Round 2
// 299.067 us; speedup vs baseline: 2.7413x; 2.7413x over previous
//
#include <hip/hip_runtime.h>

#define B_ 4
#define T_ 4096
#define C_ 1024
#define M_ (B_*T_)                 // 16384
#define BTC (B_*T_*C_)             // 16777216
#define NCHUNK 64
#define CHUNK (T_ / NCHUNK)        // 64

typedef unsigned short u16;
typedef __attribute__((ext_vector_type(8))) short bf16x8;
typedef __attribute__((ext_vector_type(4))) float f32x4;

static __device__ __forceinline__ u16 f2bf(float f) {
    unsigned u = __float_as_uint(f);
    unsigned r = (u + 0x7FFFu + ((u >> 16) & 1u)) >> 16;   // RNE
    return (u16)r;
}
static __device__ __forceinline__ float bf2f(u16 h) {
    return __uint_as_float(((unsigned)h) << 16);
}

// ---------------- prep: time-mix + bf16 cast + new_state ----------------
__global__ void prep_kernel(const float* __restrict__ x, const float* __restrict__ state,
                            const float* __restrict__ tmr, const float* __restrict__ tmk,
                            const float* __restrict__ tmv,
                            u16* __restrict__ rin, u16* __restrict__ kin, u16* __restrict__ vin,
                            float* __restrict__ new_state) {
    int idx4 = blockIdx.x * blockDim.x + threadIdx.x;
    const int n4 = BTC / 4;
    if (idx4 >= n4) return;
    const int C4 = C_ / 4;
    int c4 = idx4 % C4;
    int bt = idx4 / C4;
    int t  = bt % T_;
    int b  = bt / T_;
    float4 xc = ((const float4*)x)[idx4];
    float4 xp = (t == 0) ? ((const float4*)state)[b * C4 + c4]
                         : ((const float4*)x)[idx4 - C4];
    float4 mr = ((const float4*)tmr)[c4];
    float4 mk = ((const float4*)tmk)[c4];
    float4 mv = ((const float4*)tmv)[c4];
    ushort4 pr, pk, pv;
    pr.x = f2bf(xc.x*mr.x + xp.x*(1.f-mr.x));
    pr.y = f2bf(xc.y*mr.y + xp.y*(1.f-mr.y));
    pr.z = f2bf(xc.z*mr.z + xp.z*(1.f-mr.z));
    pr.w = f2bf(xc.w*mr.w + xp.w*(1.f-mr.w));
    pk.x = f2bf(xc.x*mk.x + xp.x*(1.f-mk.x));
    pk.y = f2bf(xc.y*mk.y + xp.y*(1.f-mk.y));
    pk.z = f2bf(xc.z*mk.z + xp.z*(1.f-mk.z));
    pk.w = f2bf(xc.w*mk.w + xp.w*(1.f-mk.w));
    pv.x = f2bf(xc.x*mv.x + xp.x*(1.f-mv.x));
    pv.y = f2bf(xc.y*mv.y + xp.y*(1.f-mv.y));
    pv.z = f2bf(xc.z*mv.z + xp.z*(1.f-mv.z));
    pv.w = f2bf(xc.w*mv.w + xp.w*(1.f-mv.w));
    ((ushort4*)rin)[idx4] = pr;
    ((ushort4*)kin)[idx4] = pk;
    ((ushort4*)vin)[idx4] = pv;
    if (t == T_ - 1) ((float4*)new_state)[b * C4 + c4] = xc;
}

// ---------------- weight cast fp32 -> bf16 ----------------
__global__ void cast_kernel(const float* __restrict__ src, u16* __restrict__ dst, int n4) {
    int i = blockIdx.x * blockDim.x + threadIdx.x;
    if (i >= n4) return;
    float4 v = ((const float4*)src)[i];
    ushort4 o;
    o.x = f2bf(v.x); o.y = f2bf(v.y); o.z = f2bf(v.z); o.w = f2bf(v.w);
    ((ushort4*)dst)[i] = o;
}

// ---------------- bf16 MFMA GEMM: C[m][n] = sum_k A[m][k] * W[n][k] ----------------
#define BM 128
#define BN 128
#define BK 32
#define EPI_SIG  0
#define EPI_EXP  1
#define EPI_BF16 2
#define EPI_F32  3

template <int EPI>
__global__ __launch_bounds__(256, 2)
void gemm_bt(const u16* __restrict__ A, const u16* __restrict__ W,
             void* __restrict__ Cptr, int M, int N, int K) {
    __shared__ u16 ldsA[2][BM * BK];
    __shared__ u16 ldsB[2][BN * BK];
    const int tid  = threadIdx.x;
    const int bn   = blockIdx.x, bm = blockIdx.y;
    const int row0 = bm * BM, col0 = bn * BN;
    const int wid  = tid >> 6, lane = tid & 63;
    const int wm   = wid >> 1, wn = wid & 1;
    const int lr   = lane & 15, kq = lane >> 4;

    f32x4 acc[4][4];
#pragma unroll
    for (int i = 0; i < 4; ++i)
#pragma unroll
        for (int j = 0; j < 4; ++j)
#pragma unroll
            for (int q = 0; q < 4; ++q) acc[i][j][q] = 0.f;

    const int rS = tid >> 2;            // 0..63
    const int kc = (tid & 3) * 8;       // 0,8,16,24

    auto stage = [&](int buf, int k0) {
#pragma unroll
        for (int h = 0; h < 2; ++h) {
            const u16* g = A + (size_t)(row0 + h * 64 + rS) * K + (k0 + kc);
            __builtin_amdgcn_global_load_lds(
                (const __attribute__((address_space(1))) void*)g,
                (__attribute__((address_space(3))) void*)&ldsA[buf][(h * 64 + rS) * BK + kc],
                16, 0, 0);
        }
#pragma unroll
        for (int h = 0; h < 2; ++h) {
            const u16* g = W + (size_t)(col0 + h * 64 + rS) * K + (k0 + kc);
            __builtin_amdgcn_global_load_lds(
                (const __attribute__((address_space(1))) void*)g,
                (__attribute__((address_space(3))) void*)&ldsB[buf][(h * 64 + rS) * BK + kc],
                16, 0, 0);
        }
    };

    stage(0, 0);
    __syncthreads();

    const int nk = K / BK;
    for (int kt = 0; kt < nk; ++kt) {
        const int cur = kt & 1;
        if (kt + 1 < nk) stage(cur ^ 1, (kt + 1) * BK);
        bf16x8 a[4], b[4];
#pragma unroll
        for (int i = 0; i < 4; ++i)
            a[i] = *(const bf16x8*)&ldsA[cur][(wm * 64 + i * 16 + lr) * BK + kq * 8];
#pragma unroll
        for (int j = 0; j < 4; ++j)
            b[j] = *(const bf16x8*)&ldsB[cur][(wn * 64 + j * 16 + lr) * BK + kq * 8];
#pragma unroll
        for (int i = 0; i < 4; ++i)
#pragma unroll
            for (int j = 0; j < 4; ++j)
                acc[i][j] = __builtin_amdgcn_mfma_f32_16x16x32_bf16(a[i], b[j], acc[i][j], 0, 0, 0);
        __syncthreads();
    }

    const int r0 = row0 + wm * 64;
    const int c0 = col0 + wn * 64;
#pragma unroll
    for (int i = 0; i < 4; ++i) {
#pragma unroll
        for (int j = 0; j < 4; ++j) {
#pragma unroll
            for (int q = 0; q < 4; ++q) {
                int rr = r0 + i * 16 + kq * 4 + q;
                int cc = c0 + j * 16 + lr;
                float v = acc[i][j][q];
                size_t o = (size_t)rr * N + cc;
                if constexpr (EPI == EPI_SIG) {
                    ((u16*)Cptr)[o] = f2bf(1.0f / (1.0f + __expf(-v)));
                } else if constexpr (EPI == EPI_EXP) {
                    ((u16*)Cptr)[o] = f2bf(__expf(v));
                } else if constexpr (EPI == EPI_BF16) {
                    ((u16*)Cptr)[o] = f2bf(v);
                } else {
                    ((float*)Cptr)[o] = v;
                }
            }
        }
    }
}

// ---------------- blocked scan: phase 1 (chunk-local partials) ----------------
// S[(b*NCHUNK + j)*C + c] = local final state of chunk j with zero init
__global__ void scan_partial(const u16* __restrict__ ek, const u16* __restrict__ vv,
                             const float* __restrict__ td, float* __restrict__ S) {
    const int tid = threadIdx.x;
    const int bid = blockIdx.x;               // [0, B_*NCHUNK*(C_/256))
    const int ct  = bid & 3;                  // C_/256 = 4 tiles
    const int j   = (bid >> 2) & (NCHUNK - 1);
    const int b   = bid >> 8;                 // /(4*NCHUNK)
    const int c   = ct * 256 + tid;
    const float d = __expf(td[c]);
    float s = 0.f;
    size_t base = ((size_t)(b * T_ + j * CHUNK)) * C_ + c;
#pragma unroll 4
    for (int t = 0; t < CHUNK; ++t) {
        size_t ix = base + (size_t)t * C_;
        s = s * d + bf2f(ek[ix]) * bf2f(vv[ix]);
    }
    S[((size_t)(b * NCHUNK + j)) * C_ + c] = s;
}

// ---------------- blocked scan: phase 2 (serial carry over chunks) ----------------
__global__ void scan_carry(const float* __restrict__ S, const float* __restrict__ td,
                           const float* __restrict__ state, float* __restrict__ carry) {
    int id = blockIdx.x * blockDim.x + threadIdx.x;
    if (id >= B_ * C_) return;
    int c = id & (C_ - 1);
    int b = id >> 10;
    float dl = __expf(td[c] * (float)CHUNK);   // d^CHUNK
    float E = state[id];                       // initial state
#pragma unroll 8
    for (int j = 0; j < NCHUNK; ++j) {
        size_t o = ((size_t)(b * NCHUNK + j)) * C_ + c;
        carry[o] = E;                          // state entering chunk j
        E = dl * E + S[o];
    }
}

// ---------------- blocked scan: phase 3 (apply carry, write out) ----------------
__global__ void scan_apply(const u16* __restrict__ ek, const u16* __restrict__ vv,
                           const u16* __restrict__ rr, const float* __restrict__ td,
                           const float* __restrict__ carry, u16* __restrict__ out) {
    const int tid = threadIdx.x;
    const int bid = blockIdx.x;
    const int ct  = bid & 3;
    const int j   = (bid >> 2) & (NCHUNK - 1);
    const int b   = bid >> 8;
    const int c   = ct * 256 + tid;
    const float d = __expf(td[c]);
    float s = carry[((size_t)(b * NCHUNK + j)) * C_ + c];
    size_t base = ((size_t)(b * T_ + j * CHUNK)) * C_ + c;
#pragma unroll 4
    for (int t = 0; t < CHUNK; ++t) {
        size_t ix = base + (size_t)t * C_;
        s = s * d + bf2f(ek[ix]) * bf2f(vv[ix]);
        out[ix] = f2bf(s * bf2f(rr[ix]));
    }
}

extern "C" void kernel_launch(void* const* d_in, const int* in_sizes, int n_in,
                              void* d_out, int out_size, void* d_ws, size_t ws_size,
                              hipStream_t stream) {
    const float* x     = (const float*)d_in[0];
    const float* state = (const float*)d_in[1];
    const float* W_r   = (const float*)d_in[2];
    const float* W_k   = (const float*)d_in[3];
    const float* W_v   = (const float*)d_in[4];
    const float* W_o   = (const float*)d_in[5];
    const float* tmr   = (const float*)d_in[6];
    const float* tmk   = (const float*)d_in[7];
    const float* tmv   = (const float*)d_in[8];
    const float* td    = (const float*)d_in[9];

    float* out_f     = (float*)d_out;          // [B,T,C] fp32
    float* new_state = out_f + (size_t)BTC;    // [B,C] fp32

    char* ws = (char*)d_ws;
    const size_t SZ = (size_t)BTC * 2;         // 33,554,432 B per bf16 buffer
    u16* rin   = (u16*)(ws + 0 * SZ);
    u16* kin   = (u16*)(ws + 1 * SZ);
    u16* vin   = (u16*)(ws + 2 * SZ);
    u16* rbuf  = (u16*)(ws + 3 * SZ);
    u16* ekbuf = (u16*)(ws + 4 * SZ);
    u16* vbuf  = (u16*)(ws + 5 * SZ);
    u16* wrb   = (u16*)(ws + 6 * SZ);
    u16* wkb   = wrb + (size_t)C_ * C_;
    u16* wvb   = wkb + (size_t)C_ * C_;
    u16* wob   = wvb + (size_t)C_ * C_;
    float* Sbuf  = (float*)(wob + (size_t)C_ * C_);              // [B*NCHUNK*C] f32 = 1 MB
    float* cbuf  = Sbuf + (size_t)B_ * NCHUNK * C_;              // [B*NCHUNK*C] f32 = 1 MB
    u16* outb  = vin;                          // overlay: vin dead after v-GEMM

    prep_kernel<<<(BTC / 4 + 255) / 256, 256, 0, stream>>>(
        x, state, tmr, tmk, tmv, rin, kin, vin, new_state);

    const int wn4 = (C_ * C_) / 4;
    cast_kernel<<<(wn4 + 255) / 256, 256, 0, stream>>>(W_r, wrb, wn4);
    cast_kernel<<<(wn4 + 255) / 256, 256, 0, stream>>>(W_k, wkb, wn4);
    cast_kernel<<<(wn4 + 255) / 256, 256, 0, stream>>>(W_v, wvb, wn4);
    cast_kernel<<<(wn4 + 255) / 256, 256, 0, stream>>>(W_o, wob, wn4);

    dim3 gg(C_ / BN, M_ / BM);   // (8, 128)
    gemm_bt<EPI_SIG ><<<gg, 256, 0, stream>>>(rin, wrb, (void*)rbuf,  M_, C_, C_);
    gemm_bt<EPI_EXP ><<<gg, 256, 0, stream>>>(kin, wkb, (void*)ekbuf, M_, C_, C_);
    gemm_bt<EPI_BF16><<<gg, 256, 0, stream>>>(vin, wvb, (void*)vbuf,  M_, C_, C_);

    const int nscan_blocks = B_ * NCHUNK * (C_ / 256);   // 1024
    scan_partial<<<nscan_blocks, 256, 0, stream>>>(ekbuf, vbuf, td, Sbuf);
    scan_carry<<<(B_ * C_ + 255) / 256, 256, 0, stream>>>(Sbuf, td, state, cbuf);
    scan_apply<<<nscan_blocks, 256, 0, stream>>>(ekbuf, vbuf, rbuf, td, cbuf, outb);

    gemm_bt<EPI_F32><<<gg, 256, 0, stream>>>(outb, wob, (void*)out_f, M_, C_, C_);
}

// Round 3
// 243.212 us; speedup vs baseline: 3.3709x; 1.2297x over previous
//
#include <hip/hip_runtime.h>

#define B_ 4
#define T_ 4096
#define C_ 1024
#define M_ (B_*T_)                 // 16384
#define BTC (B_*T_*C_)             // 16777216
#define NCHUNK 64
#define CHUNK (T_ / NCHUNK)        // 64

typedef unsigned short u16;
typedef __attribute__((ext_vector_type(8))) short bf16x8;
typedef __attribute__((ext_vector_type(4))) float f32x4;

static __device__ __forceinline__ u16 f2bf(float f) {
    unsigned u = __float_as_uint(f);
    unsigned r = (u + 0x7FFFu + ((u >> 16) & 1u)) >> 16;   // RNE
    return (u16)r;
}
static __device__ __forceinline__ float bf2f(u16 h) {
    return __uint_as_float(((unsigned)h) << 16);
}

// ---------------- prep: time-mix + bf16 cast + new_state ----------------
__global__ void prep_kernel(const float* __restrict__ x, const float* __restrict__ state,
                            const float* __restrict__ tmr, const float* __restrict__ tmk,
                            const float* __restrict__ tmv,
                            u16* __restrict__ rin, u16* __restrict__ kin, u16* __restrict__ vin,
                            float* __restrict__ new_state) {
    int idx4 = blockIdx.x * blockDim.x + threadIdx.x;
    const int n4 = BTC / 4;
    if (idx4 >= n4) return;
    const int C4 = C_ / 4;
    int c4 = idx4 % C4;
    int bt = idx4 / C4;
    int t  = bt % T_;
    int b  = bt / T_;
    float4 xc = ((const float4*)x)[idx4];
    float4 xp = (t == 0) ? ((const float4*)state)[b * C4 + c4]
                         : ((const float4*)x)[idx4 - C4];
    float4 mr = ((const float4*)tmr)[c4];
    float4 mk = ((const float4*)tmk)[c4];
    float4 mv = ((const float4*)tmv)[c4];
    ushort4 pr, pk, pv;
    pr.x = f2bf(xc.x*mr.x + xp.x*(1.f-mr.x));
    pr.y = f2bf(xc.y*mr.y + xp.y*(1.f-mr.y));
    pr.z = f2bf(xc.z*mr.z + xp.z*(1.f-mr.z));
    pr.w = f2bf(xc.w*mr.w + xp.w*(1.f-mr.w));
    pk.x = f2bf(xc.x*mk.x + xp.x*(1.f-mk.x));
    pk.y = f2bf(xc.y*mk.y + xp.y*(1.f-mk.y));
    pk.z = f2bf(xc.z*mk.z + xp.z*(1.f-mk.z));
    pk.w = f2bf(xc.w*mk.w + xp.w*(1.f-mk.w));
    pv.x = f2bf(xc.x*mv.x + xp.x*(1.f-mv.x));
    pv.y = f2bf(xc.y*mv.y + xp.y*(1.f-mv.y));
    pv.z = f2bf(xc.z*mv.z + xp.z*(1.f-mv.z));
    pv.w = f2bf(xc.w*mv.w + xp.w*(1.f-mv.w));
    ((ushort4*)rin)[idx4] = pr;
    ((ushort4*)kin)[idx4] = pk;
    ((ushort4*)vin)[idx4] = pv;
    if (t == T_ - 1) ((float4*)new_state)[b * C4 + c4] = xc;
}

// ---------------- fused weight cast fp32 -> bf16 (all 4 weights) ----------------
__global__ void cast_all_kernel(const float* __restrict__ w0, const float* __restrict__ w1,
                                const float* __restrict__ w2, const float* __restrict__ w3,
                                u16* __restrict__ dst) {
    // per weight: C_*C_/4 = 262144 float4 = 1024 blocks * 256 threads
    int w = blockIdx.x >> 10;
    int i = ((blockIdx.x & 1023) << 8) + threadIdx.x;
    const float* src = (w == 0) ? w0 : (w == 1) ? w1 : (w == 2) ? w2 : w3;
    float4 v = ((const float4*)src)[i];
    ushort4 o;
    o.x = f2bf(v.x); o.y = f2bf(v.y); o.z = f2bf(v.z); o.w = f2bf(v.w);
    ((ushort4*)(dst + (size_t)w * C_ * C_))[i] = o;
}

// ---------------- 256x256 8-wave counted-vmcnt MFMA GEMM ----------------
// C[m][n] = sum_k A[m][k] * W[n][k];  M=16384, N=1024, K=1024
#define EPI_SIG  0
#define EPI_EXP  1
#define EPI_BF16 2
#define EPI_F32  3

template <int EPI>
__global__ __launch_bounds__(512, 2)
void gemm256(const u16* __restrict__ A, const u16* __restrict__ W,
             void* __restrict__ Cptr, int M, int N, int K) {
    extern __shared__ __align__(16) u16 smem[];
    u16* sA = smem;                      // [2][256*64]
    u16* sB = smem + 2 * 256 * 64;       // [2][256*64]

    const int tid  = threadIdx.x;
    const int wid  = tid >> 6, lane = tid & 63;
    const int wr   = wid >> 2, wc = wid & 3;       // 2 x 4 wave grid
    const int lr   = lane & 15, kq = lane >> 4;

    // XCD-bijective swizzle: 256 wgs, 8 XCDs, 32/XCD; XCD gets 8 consecutive bm
    const int wg   = blockIdx.x;
    const int wgid = (wg & 7) * 32 + (wg >> 3);
    const int bm   = wgid >> 2, bn = wgid & 3;
    const int row0 = bm * 256, col0 = bn * 256;
    const int nk   = K / 64;

    f32x4 acc[8][4];
#pragma unroll
    for (int i = 0; i < 8; ++i)
#pragma unroll
        for (int j = 0; j < 4; ++j)
#pragma unroll
            for (int q = 0; q < 4; ++q) acc[i][j][q] = 0.f;

    const int rl = tid >> 3;        // 0..63 (row within 64-row stage slice)
    const int uu = tid & 7;         // 16B unit 0..7
    const int usw = uu ^ (rl & 7);  // pre-swizzled global unit

    // stage one half-tile (128 rows x 64 k) of A or B: 2 global_load_lds per thread
    auto stA = [&](int buf, int h, int kt) {
#pragma unroll
        for (int p = 0; p < 2; ++p) {
            int r  = p * 64 + rl;
            int rt = h * 128 + r;
            const u16* g = A + (size_t)(row0 + rt) * K + kt * 64 + usw * 8;
            __builtin_amdgcn_global_load_lds(
                (const __attribute__((address_space(1))) void*)g,
                (__attribute__((address_space(3))) void*)&sA[buf * 16384 + rt * 64 + uu * 8],
                16, 0, 0);
        }
    };
    auto stB = [&](int buf, int h, int kt) {
#pragma unroll
        for (int p = 0; p < 2; ++p) {
            int r  = p * 64 + rl;
            int rt = h * 128 + r;
            const u16* g = W + (size_t)(col0 + rt) * K + kt * 64 + usw * 8;
            __builtin_amdgcn_global_load_lds(
                (const __attribute__((address_space(1))) void*)g,
                (__attribute__((address_space(3))) void*)&sB[buf * 16384 + rt * 64 + uu * 8],
                16, 0, 0);
        }
    };
    // swizzled fragment reads
    auto ldA = [&](int buf, int ig, int ks) -> bf16x8 {
        int R = wr * 128 + ig * 16 + lr;
        int unit = (ks * 4 + kq) ^ (lr & 7);
        return *(const bf16x8*)&sA[buf * 16384 + R * 64 + unit * 8];
    };
    auto ldB = [&](int buf, int j, int ks) -> bf16x8 {
        int R = wc * 64 + j * 16 + lr;
        int unit = (ks * 4 + kq) ^ (lr & 7);
        return *(const bf16x8*)&sB[buf * 16384 + R * 64 + unit * 8];
    };

    // ---- prologue: tile0 (A,B) + tile1 (B only); queue: [t1.Bh0, t1.Bh1]
    stA(0, 0, 0); stA(0, 1, 0); stB(0, 0, 0); stB(0, 1, 0);
    stB(1, 0, 1); stB(1, 1, 1);
    asm volatile("s_waitcnt vmcnt(4)" ::: "memory");
    __builtin_amdgcn_s_barrier();

    for (int kt = 0; kt < nk; ++kt) {
        const int cur = kt & 1, nxt = cur ^ 1;
        const int t1 = (kt + 1 < nk) ? kt + 1 : nk - 1;
        const int t2 = (kt + 2 < nk) ? kt + 2 : nk - 1;

        bf16x8 b[4][2];
        // ---- phase 0: read all B (8) + A-frags 0,1 (4); stage t+1.Ah0 -> nxt
        bf16x8 a0[2][2];
#pragma unroll
        for (int j = 0; j < 4; ++j)
#pragma unroll
            for (int ks = 0; ks < 2; ++ks) b[j][ks] = ldB(cur, j, ks);
#pragma unroll
        for (int i = 0; i < 2; ++i)
#pragma unroll
            for (int ks = 0; ks < 2; ++ks) a0[i][ks] = ldA(cur, i, ks);
        stA(nxt, 0, t1);
        __builtin_amdgcn_sched_barrier(0);
        __builtin_amdgcn_s_setprio(1);
#pragma unroll
        for (int i = 0; i < 2; ++i)
#pragma unroll
            for (int j = 0; j < 4; ++j)
#pragma unroll
                for (int ks = 0; ks < 2; ++ks)
                    acc[i][j] = __builtin_amdgcn_mfma_f32_16x16x32_bf16(a0[i][ks], b[j][ks], acc[i][j], 0, 0, 0);
        __builtin_amdgcn_s_setprio(0);
        __builtin_amdgcn_s_barrier();

        // ---- phase 1: read A-frags 2,3; stage t+1.Ah1 -> nxt
        bf16x8 a1[2][2];
#pragma unroll
        for (int i = 0; i < 2; ++i)
#pragma unroll
            for (int ks = 0; ks < 2; ++ks) a1[i][ks] = ldA(cur, 2 + i, ks);
        stA(nxt, 1, t1);
        __builtin_amdgcn_sched_barrier(0);
        __builtin_amdgcn_s_setprio(1);
#pragma unroll
        for (int i = 0; i < 2; ++i)
#pragma unroll
            for (int j = 0; j < 4; ++j)
#pragma unroll
                for (int ks = 0; ks < 2; ++ks)
                    acc[2 + i][j] = __builtin_amdgcn_mfma_f32_16x16x32_bf16(a1[i][ks], b[j][ks], acc[2 + i][j], 0, 0, 0);
        __builtin_amdgcn_s_setprio(0);
        __builtin_amdgcn_s_barrier();

        // ---- phase 2: read A-frags 4,5; stage t+2.Bh0 -> cur (B reads drained ph0)
        bf16x8 a2[2][2];
#pragma unroll
        for (int i = 0; i < 2; ++i)
#pragma unroll
            for (int ks = 0; ks < 2; ++ks) a2[i][ks] = ldA(cur, 4 + i, ks);
        stB(cur, 0, t2);
        __builtin_amdgcn_sched_barrier(0);
        __builtin_amdgcn_s_setprio(1);
#pragma unroll
        for (int i = 0; i < 2; ++i)
#pragma unroll
            for (int j = 0; j < 4; ++j)
#pragma unroll
                for (int ks = 0; ks < 2; ++ks)
                    acc[4 + i][j] = __builtin_amdgcn_mfma_f32_16x16x32_bf16(a2[i][ks], b[j][ks], acc[4 + i][j], 0, 0, 0);
        __builtin_amdgcn_s_setprio(0);
        __builtin_amdgcn_s_barrier();

        // ---- phase 3: read A-frags 6,7; stage t+2.Bh1 -> cur; boundary vmcnt(4)
        bf16x8 a3[2][2];
#pragma unroll
        for (int i = 0; i < 2; ++i)
#pragma unroll
            for (int ks = 0; ks < 2; ++ks) a3[i][ks] = ldA(cur, 6 + i, ks);
        stB(cur, 1, t2);
        __builtin_amdgcn_sched_barrier(0);
        __builtin_amdgcn_s_setprio(1);
#pragma unroll
        for (int i = 0; i < 2; ++i)
#pragma unroll
            for (int j = 0; j < 4; ++j)
#pragma unroll
                for (int ks = 0; ks < 2; ++ks)
                    acc[6 + i][j] = __builtin_amdgcn_mfma_f32_16x16x32_bf16(a3[i][ks], b[j][ks], acc[6 + i][j], 0, 0, 0);
        __builtin_amdgcn_s_setprio(0);
        asm volatile("s_waitcnt vmcnt(4)" ::: "memory");
        __builtin_amdgcn_s_barrier();
    }

    // ---- epilogue
    const int r0 = row0 + wr * 128;
    const int c0 = col0 + wc * 64;
#pragma unroll
    for (int i = 0; i < 8; ++i) {
#pragma unroll
        for (int j = 0; j < 4; ++j) {
#pragma unroll
            for (int q = 0; q < 4; ++q) {
                int rr = r0 + i * 16 + kq * 4 + q;
                int cc = c0 + j * 16 + lr;
                float v = acc[i][j][q];
                size_t o = (size_t)rr * N + cc;
                if constexpr (EPI == EPI_SIG) {
                    ((u16*)Cptr)[o] = f2bf(1.0f / (1.0f + __expf(-v)));
                } else if constexpr (EPI == EPI_EXP) {
                    ((u16*)Cptr)[o] = f2bf(__expf(v));
                } else if constexpr (EPI == EPI_BF16) {
                    ((u16*)Cptr)[o] = f2bf(v);
                } else {
                    ((float*)Cptr)[o] = v;
                }
            }
        }
    }
}

// ---------------- blocked scan: phase 1 (chunk-local partials) ----------------
__global__ void scan_partial(const u16* __restrict__ ek, const u16* __restrict__ vv,
                             const float* __restrict__ td, float* __restrict__ S) {
    const int tid = threadIdx.x;
    const int bid = blockIdx.x;               // [0, B_*NCHUNK*(C_/256))
    const int ct  = bid & 3;
    const int j   = (bid >> 2) & (NCHUNK - 1);
    const int b   = bid >> 8;
    const int c   = ct * 256 + tid;
    const float d = __expf(td[c]);
    float s = 0.f;
    size_t base = ((size_t)(b * T_ + j * CHUNK)) * C_ + c;
#pragma unroll 4
    for (int t = 0; t < CHUNK; ++t) {
        size_t ix = base + (size_t)t * C_;
        s = s * d + bf2f(ek[ix]) * bf2f(vv[ix]);
    }
    S[((size_t)(b * NCHUNK + j)) * C_ + c] = s;
}

// ---------------- blocked scan: phase 2 (serial carry over chunks) ----------------
__global__ void scan_carry(const float* __restrict__ S, const float* __restrict__ td,
                           const float* __restrict__ state, float* __restrict__ carry) {
    int id = blockIdx.x * blockDim.x + threadIdx.x;
    if (id >= B_ * C_) return;
    int c = id & (C_ - 1);
    int b = id >> 10;
    float dl = __expf(td[c] * (float)CHUNK);   // d^CHUNK
    float E = state[id];
#pragma unroll 8
    for (int j = 0; j < NCHUNK; ++j) {
        size_t o = ((size_t)(b * NCHUNK + j)) * C_ + c;
        carry[o] = E;
        E = dl * E + S[o];
    }
}

// ---------------- blocked scan: phase 3 (apply carry, write out) ----------------
__global__ void scan_apply(const u16* __restrict__ ek, const u16* __restrict__ vv,
                           const u16* __restrict__ rr, const float* __restrict__ td,
                           const float* __restrict__ carry, u16* __restrict__ out) {
    const int tid = threadIdx.x;
    const int bid = blockIdx.x;
    const int ct  = bid & 3;
    const int j   = (bid >> 2) & (NCHUNK - 1);
    const int b   = bid >> 8;
    const int c   = ct * 256 + tid;
    const float d = __expf(td[c]);
    float s = carry[((size_t)(b * NCHUNK + j)) * C_ + c];
    size_t base = ((size_t)(b * T_ + j * CHUNK)) * C_ + c;
#pragma unroll 4
    for (int t = 0; t < CHUNK; ++t) {
        size_t ix = base + (size_t)t * C_;
        s = s * d + bf2f(ek[ix]) * bf2f(vv[ix]);
        out[ix] = f2bf(s * bf2f(rr[ix]));
    }
}

extern "C" void kernel_launch(void* const* d_in, const int* in_sizes, int n_in,
                              void* d_out, int out_size, void* d_ws, size_t ws_size,
                              hipStream_t stream) {
    const float* x     = (const float*)d_in[0];
    const float* state = (const float*)d_in[1];
    const float* W_r   = (const float*)d_in[2];
    const float* W_k   = (const float*)d_in[3];
    const float* W_v   = (const float*)d_in[4];
    const float* W_o   = (const float*)d_in[5];
    const float* tmr   = (const float*)d_in[6];
    const float* tmk   = (const float*)d_in[7];
    const float* tmv   = (const float*)d_in[8];
    const float* td    = (const float*)d_in[9];

    float* out_f     = (float*)d_out;          // [B,T,C] fp32
    float* new_state = out_f + (size_t)BTC;    // [B,C] fp32

    char* ws = (char*)d_ws;
    const size_t SZ = (size_t)BTC * 2;         // 33,554,432 B per bf16 buffer
    u16* rin   = (u16*)(ws + 0 * SZ);
    u16* kin   = (u16*)(ws + 1 * SZ);
    u16* vin   = (u16*)(ws + 2 * SZ);
    u16* rbuf  = (u16*)(ws + 3 * SZ);
    u16* ekbuf = (u16*)(ws + 4 * SZ);
    u16* vbuf  = (u16*)(ws + 5 * SZ);
    u16* wts   = (u16*)(ws + 6 * SZ);          // 4 x C*C bf16
    u16* wrb   = wts;
    u16* wkb   = wrb + (size_t)C_ * C_;
    u16* wvb   = wkb + (size_t)C_ * C_;
    u16* wob   = wvb + (size_t)C_ * C_;
    float* Sbuf  = (float*)(wob + (size_t)C_ * C_);   // 1 MB
    float* cbuf  = Sbuf + (size_t)B_ * NCHUNK * C_;   // 1 MB
    u16* outb  = vin;                          // overlay: vin dead after v-GEMM

    prep_kernel<<<(BTC / 4 + 255) / 256, 256, 0, stream>>>(
        x, state, tmr, tmk, tmv, rin, kin, vin, new_state);

    cast_all_kernel<<<4096, 256, 0, stream>>>(W_r, W_k, W_v, W_o, wts);

    const dim3 gg(256);          // (M/256)*(N/256) = 64*4
    const int LDSB = 2 * 2 * 256 * 64 * 2;     // 131072 bytes
    gemm256<EPI_SIG ><<<gg, 512, LDSB, stream>>>(rin, wrb, (void*)rbuf,  M_, C_, C_);
    gemm256<EPI_EXP ><<<gg, 512, LDSB, stream>>>(kin, wkb, (void*)ekbuf, M_, C_, C_);
    gemm256<EPI_BF16><<<gg, 512, LDSB, stream>>>(vin, wvb, (void*)vbuf,  M_, C_, C_);

    const int nscan_blocks = B_ * NCHUNK * (C_ / 256);   // 1024
    scan_partial<<<nscan_blocks, 256, 0, stream>>>(ekbuf, vbuf, td, Sbuf);
    scan_carry<<<(B_ * C_ + 255) / 256, 256, 0, stream>>>(Sbuf, td, state, cbuf);
    scan_apply<<<nscan_blocks, 256, 0, stream>>>(ekbuf, vbuf, rbuf, td, cbuf, outb);

    gemm256<EPI_F32><<<gg, 512, LDSB, stream>>>(outb, wob, (void*)out_f, M_, C_, C_);
}